// Round 8
// baseline (259.478 us; speedup 1.0000x reference)
//
#include <hip/hip_runtime.h>

// Convex upsample, fused bf16-MFMA implicit GEMM, round 8 (resubmit — round-7
// bench failed on GPU acquisition, no data for this source yet).
// R7 post-mortem: weight ping-pong prefetch negative (71.9us, MfmaUtil 21.4) —
// twice-confirmed that per-step weight LATENCY is not the chain. New model:
// GEMM1 is L2-BANDWIDTH-bound on the weight stream: all 4 waves read the same
// 73.7KB w1bf from L2 (doesn't fit 32KB L1); per-CU ~4.8MB @ 56B/clk ~= 21us.
// This round: re-decompose GEMM1 per wave [2m x 4n] -> [4m x 2n]: per-wave w1
// stream halves (36.9KB); sH becomes block-shared [128][72] (+1 barrier);
// GEMM1 LDS reads double (headroom exists). Transpose kernel unchanged (R4).
// Path B (small ws): round-2 kernel (self-staged f32), known-good fallback.

using frag_ab = __attribute__((ext_vector_type(8))) short;   // 8 bf16
using frag_cd = __attribute__((ext_vector_type(4))) float;   // 4 f32
typedef __attribute__((ext_vector_type(8))) unsigned short ushort8;

static __device__ __forceinline__ unsigned short f2bf(float f) {
    unsigned u = __builtin_bit_cast(unsigned, f);
    u += 0x7fff + ((u >> 16) & 1);          // round-to-nearest-even
    return (unsigned short)(u >> 16);
}

// ---------------- prep (fallback path only) ----------------
__global__ void prep(const float* __restrict__ w1, const float* __restrict__ w2,
                     unsigned short* __restrict__ w1bf, unsigned short* __restrict__ w2bf,
                     unsigned short* __restrict__ nhwc, int do_pad) {
    int i = blockIdx.x * 256 + threadIdx.x;
    if (i < 36864) {   // ((tap*2+kh)*4+q)*512 + oc*8 + j
        int j = i & 7, oc = (i >> 3) & 63, g = i >> 9;
        int q = g & 3, kh = (g >> 2) & 1, tap = g >> 3;
        int ic = kh * 32 + q * 8 + j;
        w1bf[i] = f2bf(w1[(oc * 64 + ic) * 9 + (tap / 3) * 3 + (tap % 3)]);
    }
    if (i < 9216) {    // ((kh*4+q)*144 + ch)*8 + j
        int j = i & 7, ch = (i >> 3) % 144, g = (i >> 3) / 144;
        int q = g & 3, kh = g >> 2;
        w2bf[i] = f2bf(w2[ch * 64 + (kh * 32 + q * 8 + j)]);
    }
    if (do_pad && i < 69888) {
        int b = i / 8736, rem = i - b * 8736;
        int pos = rem >> 3, pack = rem & 7;
        int row, w;
        if (pos < 836) { row = (pos < 418) ? 0 : 129; w = (pos < 418) ? pos : pos - 418; }
        else           { int t = pos - 836; row = 1 + (t >> 1); w = (t & 1) ? 417 : 0; }
        ushort8 z = {0, 0, 0, 0, 0, 0, 0, 0};
        *(ushort8*)&nhwc[(((size_t)b * 130 + row) * 418 + w) * 64 + pack * 8] = z;
    }
}

// ---------------- feat NCHW f32 -> padded NHWC bf16, + merged prep ----------------
__global__ __launch_bounds__(256, 8) void nchw_prep(const float* __restrict__ feat,
                                                    const float* __restrict__ w1,
                                                    const float* __restrict__ w2,
                                                    unsigned short* __restrict__ nhwc,
                                                    unsigned short* __restrict__ w1bf,
                                                    unsigned short* __restrict__ w2bf) {
    __shared__ unsigned short sT[32 * 64];   // [w][c]
    const int b = blockIdx.z, h = blockIdx.y, w0 = blockIdx.x * 32;
    const int tid = threadIdx.x;
    const int c = tid >> 2, j = tid & 3;     // 8 w-elements per thread
    const float* src = feat + (((size_t)b * 64 + c) * 128 + h) * 416 + w0 + j * 8;
    float4 v0 = *(const float4*)src;
    float4 v1 = *(const float4*)(src + 4);
    sT[(j * 8 + 0) * 64 + c] = f2bf(v0.x);
    sT[(j * 8 + 1) * 64 + c] = f2bf(v0.y);
    sT[(j * 8 + 2) * 64 + c] = f2bf(v0.z);
    sT[(j * 8 + 3) * 64 + c] = f2bf(v0.w);
    sT[(j * 8 + 4) * 64 + c] = f2bf(v1.x);
    sT[(j * 8 + 5) * 64 + c] = f2bf(v1.y);
    sT[(j * 8 + 6) * 64 + c] = f2bf(v1.z);
    sT[(j * 8 + 7) * 64 + c] = f2bf(v1.w);
    __syncthreads();
    const int w = tid >> 3, pack = tid & 7;
    ushort8 val = *(ushort8*)&sT[w * 64 + pack * 8];
    *(ushort8*)&nhwc[(((size_t)b * 130 + h + 1) * 418 + (w0 + w + 1)) * 64 + pack * 8] = val;

    // merged prep work: y==0 blocks (13 x-blocks * 8 z-blocks = 26624 threads)
    if (blockIdx.y == 0) {
        const int gid = (b * 13 + blockIdx.x) * 256 + tid;   // 0..26623
        for (int i = gid; i < 36864; i += 26624) {
            int jj = i & 7, oc = (i >> 3) & 63, g = i >> 9;
            int qq = g & 3, kh = (g >> 2) & 1, tap = g >> 3;
            int ic = kh * 32 + qq * 8 + jj;
            w1bf[i] = f2bf(w1[(oc * 64 + ic) * 9 + (tap / 3) * 3 + (tap % 3)]);
        }
        if (gid < 9216) {
            int jj = gid & 7, ch = (gid >> 3) % 144, g = (gid >> 3) / 144;
            int qq = g & 3, kh = g >> 2;
            w2bf[gid] = f2bf(w2[ch * 64 + (kh * 32 + qq * 8 + jj)]);
        }
        for (int i = gid; i < 69888; i += 26624) {
            int bb = i / 8736, rem = i - bb * 8736;
            int pos = rem >> 3, pk = rem & 7;
            int row, ww;
            if (pos < 836) { row = (pos < 418) ? 0 : 129; ww = (pos < 418) ? pos : pos - 418; }
            else           { int t = pos - 836; row = 1 + (t >> 1); ww = (t & 1) ? 417 : 0; }
            ushort8 z = {0, 0, 0, 0, 0, 0, 0, 0};
            *(ushort8*)&nhwc[(((size_t)bb * 130 + row) * 418 + ww) * 64 + pk * 8] = z;
        }
    }
}

// ---------------- main fused kernel (path A), 8h x 16w tile ----------------
// GEMM1 per-wave decomposition: wave = (mh=wv>>1, oh=wv&1) owns px rows
// mh*4..mh*4+3 x oc half oh -> halves the per-wave L2 weight stream.
__global__ __launch_bounds__(256, 4) void convex_up_mfma2(
    const float* __restrict__ depth, const unsigned short* __restrict__ nhwc,
    const unsigned short* __restrict__ w1bf, const unsigned short* __restrict__ w2bf,
    float* __restrict__ out)
{
    constexpr int H = 128, W = 416, OW = 1664;
    constexpr int RS = 418 * 64;              // padded NHWC row stride (ushorts)

    __shared__ __align__(16) unsigned short sF[1440 * 8];   // 23040 B: [r10][col18][icc8 swz][8]
    __shared__ float sD[180];

    const int tid  = threadIdx.x;
    const int wv   = tid >> 6;
    const int lane = tid & 63;
    const int q    = lane >> 4;
    const int ln   = lane & 15;
    const int oh   = wv & 1;                  // oc half (GEMM1)
    const int mh   = wv >> 1;                 // px-row quad (GEMM1)
    const int bw = blockIdx.x, bh = blockIdx.y, b = blockIdx.z;
    const int h0 = bh * 8, w0 = bw * 16;

    // depth tile (halo, zero-pad)
    if (tid < 180) {
        int lr = tid / 18, lc = tid % 18;
        int gh = h0 - 1 + lr, gw = w0 - 1 + lc;
        float v = 0.f;
        if ((unsigned)gh < (unsigned)H && (unsigned)gw < (unsigned)W)
            v = depth[((size_t)b * H + gh) * W + gw];
        sD[tid] = v;
    }

    // feat tile: 1440 16B-chunks via global_load_lds (LDS chunk c = (r*18+col)*8 + icc_swz)
    const unsigned short* gbase = nhwc + ((size_t)(b * 130 + h0) * 418 + w0) * 64;
    #pragma unroll
    for (int k = 0; k < 6; ++k) {
        int i = wv + 4 * k;
        int c = i * 64 + lane;
        if (c < 1440) {
            int r = c / 144, m = c - r * 144;
            int col = m >> 3, iccs = m & 7;
            int icc = iccs ^ (col & 7);       // XOR swizzle (source side)
            const unsigned short* g = gbase + (size_t)r * RS + col * 64 + icc * 8;
            __builtin_amdgcn_global_load_lds((const __attribute__((address_space(1))) void*)g,
                                             (__attribute__((address_space(3))) void*)&sF[c * 8],
                                             16, 0, 0);
        }
    }
    __syncthreads();

    // ---- GEMM1: conv3x3, wave owns px rows mh*4..mh*4+3 x 32 oc (half) ----
    frag_cd acc1[4][2];
    #pragma unroll
    for (int i = 0; i < 4; ++i)
        #pragma unroll
        for (int nt = 0; nt < 2; ++nt) acc1[i][nt] = frag_cd{0.f, 0.f, 0.f, 0.f};

    #pragma unroll
    for (int tap = 0; tap < 9; ++tap) {
        const int ky = tap / 3, kx = tap % 3;
        #pragma unroll
        for (int kh = 0; kh < 2; ++kh) {
            frag_ab a[4];
            #pragma unroll
            for (int i = 0; i < 4; ++i) {
                int r = mh * 4 + i + ky, col = ln + kx;
                int slot = (r * 18 + col) * 8 + ((kh * 4 + q) ^ (col & 7));
                a[i] = *(const frag_ab*)&sF[slot * 8];
            }
            frag_ab bf[2];
            #pragma unroll
            for (int nt = 0; nt < 2; ++nt)
                bf[nt] = *(const frag_ab*)&w1bf[(size_t)((tap * 2 + kh) * 4 + q) * 512
                                                + ((oh * 2 + nt) * 16 + ln) * 8];
            #pragma unroll
            for (int i = 0; i < 4; ++i)
                #pragma unroll
                for (int nt = 0; nt < 2; ++nt)
                    acc1[i][nt] = __builtin_amdgcn_mfma_f32_16x16x32_bf16(a[i], bf[nt], acc1[i][nt], 0, 0, 0);
        }
    }

    __syncthreads();   // all waves done reading sF; overlay block-shared sH

    unsigned short* sH = sF;   // block-shared [px128][72] bf16 (18432 B < 23040)
    #pragma unroll
    for (int i = 0; i < 4; ++i)
        #pragma unroll
        for (int nt = 0; nt < 2; ++nt)
            #pragma unroll
            for (int r = 0; r < 4; ++r)
                sH[((mh * 4 + i) * 16 + q * 4 + r) * 72 + (oh * 2 + nt) * 16 + ln] =
                    f2bf(fmaxf(acc1[i][nt][r], 0.f));
    __syncthreads();   // sH is cross-wave now (oc halves from paired waves)

    // ---- GEMM2: logits, n-tile == tap; wave reads px rows 2wv,2wv+1 ----
    frag_cd acc2[2][9];
    #pragma unroll
    for (int mt = 0; mt < 2; ++mt)
        #pragma unroll
        for (int nt = 0; nt < 9; ++nt) acc2[mt][nt] = frag_cd{0.f, 0.f, 0.f, 0.f};

    #pragma unroll
    for (int kh = 0; kh < 2; ++kh) {
        frag_ab a2[2];
        #pragma unroll
        for (int mt = 0; mt < 2; ++mt)
            a2[mt] = *(const frag_ab*)&sH[((2 * wv + mt) * 16 + ln) * 72 + kh * 32 + q * 8];
        #pragma unroll
        for (int nt = 0; nt < 9; ++nt) {
            frag_ab b2 = *(const frag_ab*)&w2bf[(size_t)((kh * 4 + q) * 144 + nt * 16 + ln) * 8];
            acc2[0][nt] = __builtin_amdgcn_mfma_f32_16x16x32_bf16(a2[0], b2, acc2[0][nt], 0, 0, 0);
            acc2[1][nt] = __builtin_amdgcn_mfma_f32_16x16x32_bf16(a2[1], b2, acc2[1][nt], 0, 0, 0);
        }
    }

    // ---- softmax over 9 taps + convex combine; stage into own slice ----
    // wave wv's sOutw slice = sF bytes [wv*4608, +4608) = sH px rows 32wv/..:
    // exactly the rows only THIS wave's GEMM2 read -> same-wave ordering, no barrier.
    float* sOutw = (float*)(sF + wv * 2304);   // [px32][17] f32 staging (max idx 542)
    #pragma unroll
    for (int mt = 0; mt < 2; ++mt) {
        const int prow = 2 * wv + mt;
        #pragma unroll
        for (int r = 0; r < 4; ++r) {
            const int pcol = q * 4 + r;
            float lg[9];
            #pragma unroll
            for (int t = 0; t < 9; ++t) lg[t] = acc2[mt][t][r];
            float mx = lg[0];
            #pragma unroll
            for (int t = 1; t < 9; ++t) mx = fmaxf(mx, lg[t]);
            float sum = 0.f, up = 0.f;
            #pragma unroll
            for (int t = 0; t < 9; ++t) {
                float e = __expf(lg[t] - mx);
                sum += e;
                up  += e * sD[(prow + t / 3) * 18 + (pcol + t % 3)];
            }
            sOutw[(mt * 16 + pcol) * 17 + ln] = up / sum;
        }
    }
    float* outb = out + (size_t)b * 512 * OW + (size_t)(h0 + 2 * wv) * 4 * OW + w0 * 4;
    const int row_o = lane >> 3;
    const int mt_o  = row_o >> 2, sy_o = row_o & 3;
    #pragma unroll
    for (int v = 0; v < 2; ++v) {
        float4 o;
        #pragma unroll
        for (int e = 0; e < 4; ++e) {
            int j = (lane & 7) * 8 + v * 4 + e;
            o[e] = sOutw[(mt_o * 16 + (j >> 2)) * 17 + sy_o * 4 + (j & 3)];
        }
        *(float4*)&outb[(size_t)row_o * OW + (lane & 7) * 8 + v * 4] = o;
    }
}

// ---------------- fallback (round-2 kernel, self-staged) ----------------
__global__ __launch_bounds__(256, 3) void convex_up_mfma_fb(
    const float* __restrict__ depth, const float* __restrict__ feat,
    const unsigned short* __restrict__ w1bf, const unsigned short* __restrict__ w2bf,
    float* __restrict__ out)
{
    constexpr int H = 128, W = 416, OW = 1664;
    __shared__ unsigned short sF[8 * 10 * 18 * 8];
    __shared__ unsigned short sH[4][32 * 72];
    __shared__ float sD[10 * 18];
    const int tid = threadIdx.x, wv = tid >> 6, lane = tid & 63;
    const int q = lane >> 4, ln = lane & 15;
    const int bw = blockIdx.x, bh = blockIdx.y, b = blockIdx.z;
    const int h0 = bh * 8, w0 = bw * 16;
    if (tid < 180) {
        int lr = tid / 18, lc = tid % 18;
        int gh = h0 - 1 + lr, gw = w0 - 1 + lc;
        float v = 0.f;
        if ((unsigned)gh < (unsigned)H && (unsigned)gw < (unsigned)W)
            v = depth[((size_t)b * H + gh) * W + gw];
        sD[tid] = v;
    }
    for (int idx = tid; idx < 11520; idx += 256) {
        int ic = idx / 180, rem = idx - ic * 180;
        int lr = rem / 18, lc = rem - lr * 18;
        int gh = h0 - 1 + lr, gw = w0 - 1 + lc;
        float v = 0.f;
        if ((unsigned)gh < (unsigned)H && (unsigned)gw < (unsigned)W)
            v = feat[(((size_t)b * 64 + ic) * H + gh) * W + gw];
        sF[(((ic >> 3) * 10 + lr) * 18 + lc) * 8 + (ic & 7)] = f2bf(v);
    }
    __syncthreads();
    frag_cd acc1[2][4];
    for (int mt = 0; mt < 2; ++mt) for (int nt = 0; nt < 4; ++nt) acc1[mt][nt] = frag_cd{0.f,0.f,0.f,0.f};
    #pragma unroll
    for (int tap = 0; tap < 9; ++tap) {
        const int ky = tap / 3, kx = tap % 3;
        #pragma unroll
        for (int kh = 0; kh < 2; ++kh) {
            frag_ab a[2];
            #pragma unroll
            for (int mt = 0; mt < 2; ++mt)
                a[mt] = *(const frag_ab*)&sF[(((kh * 4 + q) * 10 + 2 * wv + mt + ky) * 18 + ln + kx) * 8];
            frag_ab bf[4];
            #pragma unroll
            for (int nt = 0; nt < 4; ++nt)
                bf[nt] = *(const frag_ab*)&w1bf[(size_t)((tap * 2 + kh) * 4 + q) * 512 + (nt * 16 + ln) * 8];
            #pragma unroll
            for (int mt = 0; mt < 2; ++mt)
                #pragma unroll
                for (int nt = 0; nt < 4; ++nt)
                    acc1[mt][nt] = __builtin_amdgcn_mfma_f32_16x16x32_bf16(a[mt], bf[nt], acc1[mt][nt], 0, 0, 0);
        }
    }
    #pragma unroll
    for (int mt = 0; mt < 2; ++mt)
        #pragma unroll
        for (int nt = 0; nt < 4; ++nt)
            #pragma unroll
            for (int r = 0; r < 4; ++r)
                sH[wv][(mt * 16 + q * 4 + r) * 72 + nt * 16 + ln] = f2bf(fmaxf(acc1[mt][nt][r], 0.f));
    frag_cd acc2[2][9];
    for (int mt = 0; mt < 2; ++mt) for (int nt = 0; nt < 9; ++nt) acc2[mt][nt] = frag_cd{0.f,0.f,0.f,0.f};
    #pragma unroll
    for (int kh = 0; kh < 2; ++kh) {
        frag_ab a2[2];
        #pragma unroll
        for (int mt = 0; mt < 2; ++mt)
            a2[mt] = *(const frag_ab*)&sH[wv][(mt * 16 + ln) * 72 + kh * 32 + q * 8];
        #pragma unroll
        for (int nt = 0; nt < 9; ++nt) {
            frag_ab b2 = *(const frag_ab*)&w2bf[(size_t)((kh * 4 + q) * 144 + nt * 16 + ln) * 8];
            acc2[0][nt] = __builtin_amdgcn_mfma_f32_16x16x32_bf16(a2[0], b2, acc2[0][nt], 0, 0, 0);
            acc2[1][nt] = __builtin_amdgcn_mfma_f32_16x16x32_bf16(a2[1], b2, acc2[1][nt], 0, 0, 0);
        }
    }
    float* sOutw = (float*)&sH[wv][0];
    #pragma unroll
    for (int mt = 0; mt < 2; ++mt) {
        const int prow = 2 * wv + mt;
        #pragma unroll
        for (int r = 0; r < 4; ++r) {
            const int pcol = q * 4 + r;
            float lg[9];
            #pragma unroll
            for (int t = 0; t < 9; ++t) lg[t] = acc2[mt][t][r];
            float mx = lg[0];
            #pragma unroll
            for (int t = 1; t < 9; ++t) mx = fmaxf(mx, lg[t]);
            float sum = 0.f, up = 0.f;
            #pragma unroll
            for (int t = 0; t < 9; ++t) {
                float e = __expf(lg[t] - mx);
                sum += e; up += e * sD[(prow + t / 3) * 18 + (pcol + t % 3)];
            }
            sOutw[(mt * 16 + pcol) * 17 + ln] = up / sum;
        }
    }
    float* outb = out + (size_t)b * 512 * OW + (size_t)(h0 + 2 * wv) * 4 * OW + w0 * 4;
    const int row_o = lane >> 3, mt_o = row_o >> 2, sy_o = row_o & 3;
    #pragma unroll
    for (int v = 0; v < 2; ++v) {
        float4 o;
        #pragma unroll
        for (int e = 0; e < 4; ++e) {
            int j = (lane & 7) * 8 + v * 4 + e;
            o[e] = sOutw[(mt_o * 16 + (j >> 2)) * 17 + sy_o * 4 + (j & 3)];
        }
        *(float4*)&outb[(size_t)row_o * OW + (lane & 7) * 8 + v * 4] = o;
    }
}

extern "C" void kernel_launch(void* const* d_in, const int* in_sizes, int n_in,
                              void* d_out, int out_size, void* d_ws, size_t ws_size,
                              hipStream_t stream) {
    const float* depth = (const float*)d_in[0];
    const float* feat  = (const float*)d_in[1];
    const float* w1    = (const float*)d_in[2];
    const float* w2    = (const float*)d_in[3];
    float* out = (float*)d_out;

    const size_t NHWC_USHORTS = (size_t)8 * 130 * 418 * 64;        // 27,827,200
    const size_t NEED = NHWC_USHORTS * 2 + (36864 + 9216) * 2;     // 55,746,560 B

    if (ws_size >= NEED) {
        unsigned short* nhwc = (unsigned short*)d_ws;
        unsigned short* w1bf = nhwc + NHWC_USHORTS;
        unsigned short* w2bf = w1bf + 36864;
        nchw_prep<<<dim3(13, 128, 8), 256, 0, stream>>>(feat, w1, w2, nhwc, w1bf, w2bf);
        convex_up_mfma2<<<dim3(26, 16, 8), dim3(256), 0, stream>>>(depth, nhwc, w1bf, w2bf, out);
    } else {
        unsigned short* w1bf = (unsigned short*)d_ws;
        unsigned short* w2bf = w1bf + 36864;
        prep<<<273, 256, 0, stream>>>(w1, w2, w1bf, w2bf, nullptr, 0);
        convex_up_mfma_fb<<<dim3(26, 16, 8), 256, 0, stream>>>(depth, feat, w1bf, w2bf, out);
    }
}

// Round 13
// 239.213 us; speedup vs baseline: 1.0847x; 1.0847x over previous
//
#include <hip/hip_runtime.h>

// Convex upsample, fused bf16-MFMA implicit GEMM, round 9 (resubmit x4 — rounds
// 9-12 all failed on GPU acquisition; source still unmeasured).
// R8 post-mortem: [4m x 2n] wave re-split regressed hard (88us, MfmaUtil 17.5,
// staging L2-hit 46%->0%, nhwc writebacks in-window) — weight-L2-BW theory
// falsified, as were weight-latency (R4/R7) and setprio (R5) theories. All
// four main-kernel experiments regressed; only the original 68.5us structure
// is verified good. This round: exact R0 main + merged 2-dispatch prep, ONE
// micro-delta: issue the global_load_lds DMA BEFORE the depth-tile load so
// depth loads + sD writes overlap the DMA latency (was serial before issue).
// Path B (small ws): round-2 kernel (self-staged f32), known-good fallback.

using frag_ab = __attribute__((ext_vector_type(8))) short;   // 8 bf16
using frag_cd = __attribute__((ext_vector_type(4))) float;   // 4 f32
typedef __attribute__((ext_vector_type(8))) unsigned short ushort8;

static __device__ __forceinline__ unsigned short f2bf(float f) {
    unsigned u = __builtin_bit_cast(unsigned, f);
    u += 0x7fff + ((u >> 16) & 1);          // round-to-nearest-even
    return (unsigned short)(u >> 16);
}

// ---------------- prep (fallback path only) ----------------
__global__ void prep(const float* __restrict__ w1, const float* __restrict__ w2,
                     unsigned short* __restrict__ w1bf, unsigned short* __restrict__ w2bf,
                     unsigned short* __restrict__ nhwc, int do_pad) {
    int i = blockIdx.x * 256 + threadIdx.x;
    if (i < 36864) {   // ((tap*2+kh)*4+q)*512 + oc*8 + j
        int j = i & 7, oc = (i >> 3) & 63, g = i >> 9;
        int q = g & 3, kh = (g >> 2) & 1, tap = g >> 3;
        int ic = kh * 32 + q * 8 + j;
        w1bf[i] = f2bf(w1[(oc * 64 + ic) * 9 + (tap / 3) * 3 + (tap % 3)]);
    }
    if (i < 9216) {    // ((kh*4+q)*144 + ch)*8 + j
        int j = i & 7, ch = (i >> 3) % 144, g = (i >> 3) / 144;
        int q = g & 3, kh = g >> 2;
        w2bf[i] = f2bf(w2[ch * 64 + (kh * 32 + q * 8 + j)]);
    }
    if (do_pad && i < 69888) {
        int b = i / 8736, rem = i - b * 8736;
        int pos = rem >> 3, pack = rem & 7;
        int row, w;
        if (pos < 836) { row = (pos < 418) ? 0 : 129; w = (pos < 418) ? pos : pos - 418; }
        else           { int t = pos - 836; row = 1 + (t >> 1); w = (t & 1) ? 417 : 0; }
        ushort8 z = {0, 0, 0, 0, 0, 0, 0, 0};
        *(ushort8*)&nhwc[(((size_t)b * 130 + row) * 418 + w) * 64 + pack * 8] = z;
    }
}

// ---------------- feat NCHW f32 -> padded NHWC bf16, + merged prep ----------------
__global__ __launch_bounds__(256, 8) void nchw_prep(const float* __restrict__ feat,
                                                    const float* __restrict__ w1,
                                                    const float* __restrict__ w2,
                                                    unsigned short* __restrict__ nhwc,
                                                    unsigned short* __restrict__ w1bf,
                                                    unsigned short* __restrict__ w2bf) {
    __shared__ unsigned short sT[32 * 64];   // [w][c]
    const int b = blockIdx.z, h = blockIdx.y, w0 = blockIdx.x * 32;
    const int tid = threadIdx.x;
    const int c = tid >> 2, j = tid & 3;     // 8 w-elements per thread
    const float* src = feat + (((size_t)b * 64 + c) * 128 + h) * 416 + w0 + j * 8;
    float4 v0 = *(const float4*)src;
    float4 v1 = *(const float4*)(src + 4);
    sT[(j * 8 + 0) * 64 + c] = f2bf(v0.x);
    sT[(j * 8 + 1) * 64 + c] = f2bf(v0.y);
    sT[(j * 8 + 2) * 64 + c] = f2bf(v0.z);
    sT[(j * 8 + 3) * 64 + c] = f2bf(v0.w);
    sT[(j * 8 + 4) * 64 + c] = f2bf(v1.x);
    sT[(j * 8 + 5) * 64 + c] = f2bf(v1.y);
    sT[(j * 8 + 6) * 64 + c] = f2bf(v1.z);
    sT[(j * 8 + 7) * 64 + c] = f2bf(v1.w);
    __syncthreads();
    const int w = tid >> 3, pack = tid & 7;
    ushort8 val = *(ushort8*)&sT[w * 64 + pack * 8];
    *(ushort8*)&nhwc[(((size_t)b * 130 + h + 1) * 418 + (w0 + w + 1)) * 64 + pack * 8] = val;

    // merged prep work: y==0 blocks (13 x-blocks * 8 z-blocks = 26624 threads)
    if (blockIdx.y == 0) {
        const int gid = (b * 13 + blockIdx.x) * 256 + tid;   // 0..26623
        for (int i = gid; i < 36864; i += 26624) {
            int jj = i & 7, oc = (i >> 3) & 63, g = i >> 9;
            int qq = g & 3, kh = (g >> 2) & 1, tap = g >> 3;
            int ic = kh * 32 + qq * 8 + jj;
            w1bf[i] = f2bf(w1[(oc * 64 + ic) * 9 + (tap / 3) * 3 + (tap % 3)]);
        }
        if (gid < 9216) {
            int jj = gid & 7, ch = (gid >> 3) % 144, g = (gid >> 3) / 144;
            int qq = g & 3, kh = g >> 2;
            w2bf[gid] = f2bf(w2[ch * 64 + (kh * 32 + qq * 8 + jj)]);
        }
        for (int i = gid; i < 69888; i += 26624) {
            int bb = i / 8736, rem = i - bb * 8736;
            int pos = rem >> 3, pk = rem & 7;
            int row, ww;
            if (pos < 836) { row = (pos < 418) ? 0 : 129; ww = (pos < 418) ? pos : pos - 418; }
            else           { int t = pos - 836; row = 1 + (t >> 1); ww = (t & 1) ? 417 : 0; }
            ushort8 z = {0, 0, 0, 0, 0, 0, 0, 0};
            *(ushort8*)&nhwc[(((size_t)bb * 130 + row) * 418 + ww) * 64 + pk * 8] = z;
        }
    }
}

// ---------------- main fused kernel (path A), 8h x 16w tile ----------------
__global__ __launch_bounds__(256, 4) void convex_up_mfma2(
    const float* __restrict__ depth, const unsigned short* __restrict__ nhwc,
    const unsigned short* __restrict__ w1bf, const unsigned short* __restrict__ w2bf,
    float* __restrict__ out)
{
    constexpr int H = 128, W = 416, OW = 1664;
    constexpr int RS = 418 * 64;              // padded NHWC row stride (ushorts)

    __shared__ __align__(16) unsigned short sF[1440 * 8];   // 23040 B: [r10][col18][icc8 swz][8]
    __shared__ float sD[180];

    const int tid  = threadIdx.x;
    const int wv   = tid >> 6;
    const int lane = tid & 63;
    const int q    = lane >> 4;
    const int ln   = lane & 15;
    const int bw = blockIdx.x, bh = blockIdx.y, b = blockIdx.z;
    const int h0 = bh * 8, w0 = bw * 16;

    // feat tile FIRST: 1440 16B-chunks via global_load_lds — long-latency DMA
    // issued before the depth loads so they overlap it.
    const unsigned short* gbase = nhwc + ((size_t)(b * 130 + h0) * 418 + w0) * 64;
    #pragma unroll
    for (int k = 0; k < 6; ++k) {
        int i = wv + 4 * k;
        int c = i * 64 + lane;
        if (c < 1440) {
            int r = c / 144, m = c - r * 144;
            int col = m >> 3, iccs = m & 7;
            int icc = iccs ^ (col & 7);       // XOR swizzle (source side)
            const unsigned short* g = gbase + (size_t)r * RS + col * 64 + icc * 8;
            __builtin_amdgcn_global_load_lds((const __attribute__((address_space(1))) void*)g,
                                             (__attribute__((address_space(3))) void*)&sF[c * 8],
                                             16, 0, 0);
        }
    }

    // depth tile (halo, zero-pad) — overlaps the in-flight DMA
    if (tid < 180) {
        int lr = tid / 18, lc = tid % 18;
        int gh = h0 - 1 + lr, gw = w0 - 1 + lc;
        float v = 0.f;
        if ((unsigned)gh < (unsigned)H && (unsigned)gw < (unsigned)W)
            v = depth[((size_t)b * H + gh) * W + gw];
        sD[tid] = v;
    }
    __syncthreads();

    // ---- GEMM1: conv3x3, wave owns px rows 2wv,2wv+1 x 64 oc ----
    frag_cd acc1[2][4];
    #pragma unroll
    for (int mt = 0; mt < 2; ++mt)
        #pragma unroll
        for (int nt = 0; nt < 4; ++nt) acc1[mt][nt] = frag_cd{0.f, 0.f, 0.f, 0.f};

    #pragma unroll
    for (int tap = 0; tap < 9; ++tap) {
        const int ky = tap / 3, kx = tap % 3;
        #pragma unroll
        for (int kh = 0; kh < 2; ++kh) {
            frag_ab a[2];
            #pragma unroll
            for (int mt = 0; mt < 2; ++mt) {
                int r = 2 * wv + mt + ky, col = ln + kx;
                int slot = (r * 18 + col) * 8 + ((kh * 4 + q) ^ (col & 7));
                a[mt] = *(const frag_ab*)&sF[slot * 8];
            }
            frag_ab bf[4];
            #pragma unroll
            for (int nt = 0; nt < 4; ++nt)
                bf[nt] = *(const frag_ab*)&w1bf[(size_t)((tap * 2 + kh) * 4 + q) * 512 + (nt * 16 + ln) * 8];
            #pragma unroll
            for (int mt = 0; mt < 2; ++mt)
                #pragma unroll
                for (int nt = 0; nt < 4; ++nt)
                    acc1[mt][nt] = __builtin_amdgcn_mfma_f32_16x16x32_bf16(a[mt], bf[nt], acc1[mt][nt], 0, 0, 0);
        }
    }

    __syncthreads();   // all waves done reading sF; overlay sH on it

    unsigned short* sH = sF + wv * 2304;   // per-wave [px32][72] bf16 (4608 B slice)
    #pragma unroll
    for (int mt = 0; mt < 2; ++mt)
        #pragma unroll
        for (int nt = 0; nt < 4; ++nt)
            #pragma unroll
            for (int r = 0; r < 4; ++r)
                sH[(mt * 16 + q * 4 + r) * 72 + nt * 16 + ln] = f2bf(fmaxf(acc1[mt][nt][r], 0.f));
    // same-wave LDS RAW: compiler-inserted lgkmcnt, no barrier needed

    // ---- GEMM2: logits, n-tile == tap ----
    frag_cd acc2[2][9];
    #pragma unroll
    for (int mt = 0; mt < 2; ++mt)
        #pragma unroll
        for (int nt = 0; nt < 9; ++nt) acc2[mt][nt] = frag_cd{0.f, 0.f, 0.f, 0.f};

    #pragma unroll
    for (int kh = 0; kh < 2; ++kh) {
        frag_ab a2[2];
        #pragma unroll
        for (int mt = 0; mt < 2; ++mt)
            a2[mt] = *(const frag_ab*)&sH[(mt * 16 + ln) * 72 + kh * 32 + q * 8];
        #pragma unroll
        for (int nt = 0; nt < 9; ++nt) {
            frag_ab b2 = *(const frag_ab*)&w2bf[(size_t)((kh * 4 + q) * 144 + nt * 16 + ln) * 8];
            acc2[0][nt] = __builtin_amdgcn_mfma_f32_16x16x32_bf16(a2[0], b2, acc2[0][nt], 0, 0, 0);
            acc2[1][nt] = __builtin_amdgcn_mfma_f32_16x16x32_bf16(a2[1], b2, acc2[1][nt], 0, 0, 0);
        }
    }

    // ---- softmax over 9 taps + convex combine; stage into own slice ----
    float* sOutw = (float*)sH;   // [px32][17] f32 staging (max idx 542 < 1152 f32 slice)
    #pragma unroll
    for (int mt = 0; mt < 2; ++mt) {
        const int prow = 2 * wv + mt;
        #pragma unroll
        for (int r = 0; r < 4; ++r) {
            const int pcol = q * 4 + r;
            float lg[9];
            #pragma unroll
            for (int t = 0; t < 9; ++t) lg[t] = acc2[mt][t][r];
            float mx = lg[0];
            #pragma unroll
            for (int t = 1; t < 9; ++t) mx = fmaxf(mx, lg[t]);
            float sum = 0.f, up = 0.f;
            #pragma unroll
            for (int t = 0; t < 9; ++t) {
                float e = __expf(lg[t] - mx);
                sum += e;
                up  += e * sD[(prow + t / 3) * 18 + (pcol + t % 3)];
            }
            sOutw[(mt * 16 + pcol) * 17 + ln] = up / sum;
        }
    }
    float* outb = out + (size_t)b * 512 * OW + (size_t)(h0 + 2 * wv) * 4 * OW + w0 * 4;
    const int row_o = lane >> 3;
    const int mt_o  = row_o >> 2, sy_o = row_o & 3;
    #pragma unroll
    for (int v = 0; v < 2; ++v) {
        float4 o;
        #pragma unroll
        for (int e = 0; e < 4; ++e) {
            int j = (lane & 7) * 8 + v * 4 + e;
            o[e] = sOutw[(mt_o * 16 + (j >> 2)) * 17 + sy_o * 4 + (j & 3)];
        }
        *(float4*)&outb[(size_t)row_o * OW + (lane & 7) * 8 + v * 4] = o;
    }
}

// ---------------- fallback (round-2 kernel, self-staged) ----------------
__global__ __launch_bounds__(256, 3) void convex_up_mfma_fb(
    const float* __restrict__ depth, const float* __restrict__ feat,
    const unsigned short* __restrict__ w1bf, const unsigned short* __restrict__ w2bf,
    float* __restrict__ out)
{
    constexpr int H = 128, W = 416, OW = 1664;
    __shared__ unsigned short sF[8 * 10 * 18 * 8];
    __shared__ unsigned short sH[4][32 * 72];
    __shared__ float sD[10 * 18];
    const int tid = threadIdx.x, wv = tid >> 6, lane = tid & 63;
    const int q = lane >> 4, ln = lane & 15;
    const int bw = blockIdx.x, bh = blockIdx.y, b = blockIdx.z;
    const int h0 = bh * 8, w0 = bw * 16;
    if (tid < 180) {
        int lr = tid / 18, lc = tid % 18;
        int gh = h0 - 1 + lr, gw = w0 - 1 + lc;
        float v = 0.f;
        if ((unsigned)gh < (unsigned)H && (unsigned)gw < (unsigned)W)
            v = depth[((size_t)b * H + gh) * W + gw];
        sD[tid] = v;
    }
    for (int idx = tid; idx < 11520; idx += 256) {
        int ic = idx / 180, rem = idx - ic * 180;
        int lr = rem / 18, lc = rem - lr * 18;
        int gh = h0 - 1 + lr, gw = w0 - 1 + lc;
        float v = 0.f;
        if ((unsigned)gh < (unsigned)H && (unsigned)gw < (unsigned)W)
            v = feat[(((size_t)b * 64 + ic) * H + gh) * W + gw];
        sF[(((ic >> 3) * 10 + lr) * 18 + lc) * 8 + (ic & 7)] = f2bf(v);
    }
    __syncthreads();
    frag_cd acc1[2][4];
    for (int mt = 0; mt < 2; ++mt) for (int nt = 0; nt < 4; ++nt) acc1[mt][nt] = frag_cd{0.f,0.f,0.f,0.f};
    #pragma unroll
    for (int tap = 0; tap < 9; ++tap) {
        const int ky = tap / 3, kx = tap % 3;
        #pragma unroll
        for (int kh = 0; kh < 2; ++kh) {
            frag_ab a[2];
            #pragma unroll
            for (int mt = 0; mt < 2; ++mt)
                a[mt] = *(const frag_ab*)&sF[(((kh * 4 + q) * 10 + 2 * wv + mt + ky) * 18 + ln + kx) * 8];
            frag_ab bf[4];
            #pragma unroll
            for (int nt = 0; nt < 4; ++nt)
                bf[nt] = *(const frag_ab*)&w1bf[(size_t)((tap * 2 + kh) * 4 + q) * 512 + (nt * 16 + ln) * 8];
            #pragma unroll
            for (int mt = 0; mt < 2; ++mt)
                #pragma unroll
                for (int nt = 0; nt < 4; ++nt)
                    acc1[mt][nt] = __builtin_amdgcn_mfma_f32_16x16x32_bf16(a[mt], bf[nt], acc1[mt][nt], 0, 0, 0);
        }
    }
    #pragma unroll
    for (int mt = 0; mt < 2; ++mt)
        #pragma unroll
        for (int nt = 0; nt < 4; ++nt)
            #pragma unroll
            for (int r = 0; r < 4; ++r)
                sH[wv][(mt * 16 + q * 4 + r) * 72 + nt * 16 + ln] = f2bf(fmaxf(acc1[mt][nt][r], 0.f));
    frag_cd acc2[2][9];
    for (int mt = 0; mt < 2; ++mt) for (int nt = 0; nt < 9; ++nt) acc2[mt][nt] = frag_cd{0.f,0.f,0.f,0.f};
    #pragma unroll
    for (int kh = 0; kh < 2; ++kh) {
        frag_ab a2[2];
        #pragma unroll
        for (int mt = 0; mt < 2; ++mt)
            a2[mt] = *(const frag_ab*)&sH[wv][(mt * 16 + ln) * 72 + kh * 32 + q * 8];
        #pragma unroll
        for (int nt = 0; nt < 9; ++nt) {
            frag_ab b2 = *(const frag_ab*)&w2bf[(size_t)((kh * 4 + q) * 144 + nt * 16 + ln) * 8];
            acc2[0][nt] = __builtin_amdgcn_mfma_f32_16x16x32_bf16(a2[0], b2, acc2[0][nt], 0, 0, 0);
            acc2[1][nt] = __builtin_amdgcn_mfma_f32_16x16x32_bf16(a2[1], b2, acc2[1][nt], 0, 0, 0);
        }
    }
    float* sOutw = (float*)&sH[wv][0];
    #pragma unroll
    for (int mt = 0; mt < 2; ++mt) {
        const int prow = 2 * wv + mt;
        #pragma unroll
        for (int r = 0; r < 4; ++r) {
            const int pcol = q * 4 + r;
            float lg[9];
            #pragma unroll
            for (int t = 0; t < 9; ++t) lg[t] = acc2[mt][t][r];
            float mx = lg[0];
            #pragma unroll
            for (int t = 1; t < 9; ++t) mx = fmaxf(mx, lg[t]);
            float sum = 0.f, up = 0.f;
            #pragma unroll
            for (int t = 0; t < 9; ++t) {
                float e = __expf(lg[t] - mx);
                sum += e; up += e * sD[(prow + t / 3) * 18 + (pcol + t % 3)];
            }
            sOutw[(mt * 16 + pcol) * 17 + ln] = up / sum;
        }
    }
    float* outb = out + (size_t)b * 512 * OW + (size_t)(h0 + 2 * wv) * 4 * OW + w0 * 4;
    const int row_o = lane >> 3, mt_o = row_o >> 2, sy_o = row_o & 3;
    #pragma unroll
    for (int v = 0; v < 2; ++v) {
        float4 o;
        #pragma unroll
        for (int e = 0; e < 4; ++e) {
            int j = (lane & 7) * 8 + v * 4 + e;
            o[e] = sOutw[(mt_o * 16 + (j >> 2)) * 17 + sy_o * 4 + (j & 3)];
        }
        *(float4*)&outb[(size_t)row_o * OW + (lane & 7) * 8 + v * 4] = o;
    }
}

extern "C" void kernel_launch(void* const* d_in, const int* in_sizes, int n_in,
                              void* d_out, int out_size, void* d_ws, size_t ws_size,
                              hipStream_t stream) {
    const float* depth = (const float*)d_in[0];
    const float* feat  = (const float*)d_in[1];
    const float* w1    = (const float*)d_in[2];
    const float* w2    = (const float*)d_in[3];
    float* out = (float*)d_out;

    const size_t NHWC_USHORTS = (size_t)8 * 130 * 418 * 64;        // 27,827,200
    const size_t NEED = NHWC_USHORTS * 2 + (36864 + 9216) * 2;     // 55,746,560 B

    if (ws_size >= NEED) {
        unsigned short* nhwc = (unsigned short*)d_ws;
        unsigned short* w1bf = nhwc + NHWC_USHORTS;
        unsigned short* w2bf = w1bf + 36864;
        nchw_prep<<<dim3(13, 128, 8), 256, 0, stream>>>(feat, w1, w2, nhwc, w1bf, w2bf);
        convex_up_mfma2<<<dim3(26, 16, 8), dim3(256), 0, stream>>>(depth, nhwc, w1bf, w2bf, out);
    } else {
        unsigned short* w1bf = (unsigned short*)d_ws;
        unsigned short* w2bf = w1bf + 36864;
        prep<<<273, 256, 0, stream>>>(w1, w2, w1bf, w2bf, nullptr, 0);
        convex_up_mfma_fb<<<dim3(26, 16, 8), 256, 0, stream>>>(depth, feat, w1bf, w2bf, out);
    }
}

// Round 15
// 237.951 us; speedup vs baseline: 1.0905x; 1.0053x over previous
//
#include <hip/hip_runtime.h>

// Convex upsample, fused bf16-MFMA implicit GEMM, round 10 (resubmit — round-14
// bench failed on GPU acquisition; source unmeasured).
// R13 (measured): DMA-first main = 68.2-69.9us (baseline-equal, keep);
// total 239.2us = session best. Main kernel plateau confirmed 5x; remaining
// addressable slack is the transpose: old sT layout has a structural 8-16-way
// LDS WRITE conflict (any 16B-aligned stride makes bank independent of j) in
// 13312 tiny blocks. This round: LDS-free transpose with 8B/lane stores —
// thread owns a channel-quad x w-octet, reads 8 coalesced float4 (4 NCHW
// planes), packs 4 ch -> ushort4, stores 8B (wave = 4x128B segments). No LDS,
// no barrier, 4 h-rows/block (3328 blocks). Main kernel BYTE-IDENTICAL to the
// measured R13 source (attribution via total - main).
// Path B (small ws): round-2 kernel (self-staged f32), known-good fallback.

using frag_ab = __attribute__((ext_vector_type(8))) short;   // 8 bf16
using frag_cd = __attribute__((ext_vector_type(4))) float;   // 4 f32
typedef __attribute__((ext_vector_type(8))) unsigned short ushort8;
typedef __attribute__((ext_vector_type(4))) unsigned short ushort4_t;

static __device__ __forceinline__ unsigned short f2bf(float f) {
    unsigned u = __builtin_bit_cast(unsigned, f);
    u += 0x7fff + ((u >> 16) & 1);          // round-to-nearest-even
    return (unsigned short)(u >> 16);
}

// ---------------- prep (fallback path only) ----------------
__global__ void prep(const float* __restrict__ w1, const float* __restrict__ w2,
                     unsigned short* __restrict__ w1bf, unsigned short* __restrict__ w2bf,
                     unsigned short* __restrict__ nhwc, int do_pad) {
    int i = blockIdx.x * 256 + threadIdx.x;
    if (i < 36864) {   // ((tap*2+kh)*4+q)*512 + oc*8 + j
        int j = i & 7, oc = (i >> 3) & 63, g = i >> 9;
        int q = g & 3, kh = (g >> 2) & 1, tap = g >> 3;
        int ic = kh * 32 + q * 8 + j;
        w1bf[i] = f2bf(w1[(oc * 64 + ic) * 9 + (tap / 3) * 3 + (tap % 3)]);
    }
    if (i < 9216) {    // ((kh*4+q)*144 + ch)*8 + j
        int j = i & 7, ch = (i >> 3) % 144, g = (i >> 3) / 144;
        int q = g & 3, kh = g >> 2;
        w2bf[i] = f2bf(w2[ch * 64 + (kh * 32 + q * 8 + j)]);
    }
    if (do_pad && i < 69888) {
        int b = i / 8736, rem = i - b * 8736;
        int pos = rem >> 3, pack = rem & 7;
        int row, w;
        if (pos < 836) { row = (pos < 418) ? 0 : 129; w = (pos < 418) ? pos : pos - 418; }
        else           { int t = pos - 836; row = 1 + (t >> 1); w = (t & 1) ? 417 : 0; }
        ushort8 z = {0, 0, 0, 0, 0, 0, 0, 0};
        *(ushort8*)&nhwc[(((size_t)b * 130 + row) * 418 + w) * 64 + pack * 8] = z;
    }
}

// ------- feat NCHW f32 -> padded NHWC bf16 (LDS-free, 8B stores), + merged prep -------
// Block covers 4 h-rows x 32 w. Thread: hh = tid>>6 (h row), c4 = lane&15
// (channel quad), ws = lane>>4 (w octet). Reads 8x float4 (4 planes x 8 w,
// coalesced 64B per c4-group); packs 4 channels -> ushort4 per w; stores 8B
// (16 c4-lanes = 128B contiguous NHWC segment per w).
__global__ __launch_bounds__(256, 8) void nchw_prep(const float* __restrict__ feat,
                                                    const float* __restrict__ w1,
                                                    const float* __restrict__ w2,
                                                    unsigned short* __restrict__ nhwc,
                                                    unsigned short* __restrict__ w1bf,
                                                    unsigned short* __restrict__ w2bf) {
    const int b = blockIdx.z, h4 = blockIdx.y, w0 = blockIdx.x * 32;
    const int tid = threadIdx.x;
    const int hh = tid >> 6;             // 0-3
    const int l  = tid & 63;
    const int c4 = l & 15;               // channels c4*4 .. c4*4+3
    const int ws = l >> 4;               // 0-3, 8 w each
    const int h  = h4 * 4 + hh;
    const int wb = w0 + ws * 8;
    const size_t plane = (size_t)128 * 416;
    const float* src = feat + (((size_t)b * 64 + c4 * 4) * 128 + h) * 416 + wb;

    float vv[4][8];
    #pragma unroll
    for (int i = 0; i < 4; ++i) {
        float4 a = *(const float4*)(src + i * plane);
        float4 c = *(const float4*)(src + i * plane + 4);
        vv[i][0] = a.x; vv[i][1] = a.y; vv[i][2] = a.z; vv[i][3] = a.w;
        vv[i][4] = c.x; vv[i][5] = c.y; vv[i][6] = c.z; vv[i][7] = c.w;
    }
    unsigned short* dst = nhwc + (((size_t)(b * 130) + h + 1) * 418 + (wb + 1)) * 64 + c4 * 4;
    #pragma unroll
    for (int w = 0; w < 8; ++w) {
        ushort4_t p = {f2bf(vv[0][w]), f2bf(vv[1][w]), f2bf(vv[2][w]), f2bf(vv[3][w])};
        *(ushort4_t*)&dst[(size_t)w * 64] = p;
    }

    // merged prep work: y==0 blocks (13 x-blocks * 8 z-blocks = 26624 threads)
    if (blockIdx.y == 0) {
        const int gid = (b * 13 + blockIdx.x) * 256 + tid;   // 0..26623
        for (int i = gid; i < 36864; i += 26624) {
            int jj = i & 7, oc = (i >> 3) & 63, g = i >> 9;
            int qq = g & 3, kh = (g >> 2) & 1, tap = g >> 3;
            int ic = kh * 32 + qq * 8 + jj;
            w1bf[i] = f2bf(w1[(oc * 64 + ic) * 9 + (tap / 3) * 3 + (tap % 3)]);
        }
        if (gid < 9216) {
            int jj = gid & 7, ch = (gid >> 3) % 144, g = (gid >> 3) / 144;
            int qq = g & 3, kh = g >> 2;
            w2bf[gid] = f2bf(w2[ch * 64 + (kh * 32 + qq * 8 + jj)]);
        }
        for (int i = gid; i < 69888; i += 26624) {
            int bb = i / 8736, rem = i - bb * 8736;
            int pos = rem >> 3, pk = rem & 7;
            int row, ww;
            if (pos < 836) { row = (pos < 418) ? 0 : 129; ww = (pos < 418) ? pos : pos - 418; }
            else           { int t = pos - 836; row = 1 + (t >> 1); ww = (t & 1) ? 417 : 0; }
            ushort8 z = {0, 0, 0, 0, 0, 0, 0, 0};
            *(ushort8*)&nhwc[(((size_t)bb * 130 + row) * 418 + ww) * 64 + pk * 8] = z;
        }
    }
}

// ---------------- main fused kernel (path A), 8h x 16w tile ----------------
// BYTE-IDENTICAL to the measured R13 source (68.2-69.9us).
__global__ __launch_bounds__(256, 4) void convex_up_mfma2(
    const float* __restrict__ depth, const unsigned short* __restrict__ nhwc,
    const unsigned short* __restrict__ w1bf, const unsigned short* __restrict__ w2bf,
    float* __restrict__ out)
{
    constexpr int H = 128, W = 416, OW = 1664;
    constexpr int RS = 418 * 64;              // padded NHWC row stride (ushorts)

    __shared__ __align__(16) unsigned short sF[1440 * 8];   // 23040 B: [r10][col18][icc8 swz][8]
    __shared__ float sD[180];

    const int tid  = threadIdx.x;
    const int wv   = tid >> 6;
    const int lane = tid & 63;
    const int q    = lane >> 4;
    const int ln   = lane & 15;
    const int bw = blockIdx.x, bh = blockIdx.y, b = blockIdx.z;
    const int h0 = bh * 8, w0 = bw * 16;

    // feat tile FIRST: 1440 16B-chunks via global_load_lds — long-latency DMA
    // issued before the depth loads so they overlap it.
    const unsigned short* gbase = nhwc + ((size_t)(b * 130 + h0) * 418 + w0) * 64;
    #pragma unroll
    for (int k = 0; k < 6; ++k) {
        int i = wv + 4 * k;
        int c = i * 64 + lane;
        if (c < 1440) {
            int r = c / 144, m = c - r * 144;
            int col = m >> 3, iccs = m & 7;
            int icc = iccs ^ (col & 7);       // XOR swizzle (source side)
            const unsigned short* g = gbase + (size_t)r * RS + col * 64 + icc * 8;
            __builtin_amdgcn_global_load_lds((const __attribute__((address_space(1))) void*)g,
                                             (__attribute__((address_space(3))) void*)&sF[c * 8],
                                             16, 0, 0);
        }
    }

    // depth tile (halo, zero-pad) — overlaps the in-flight DMA
    if (tid < 180) {
        int lr = tid / 18, lc = tid % 18;
        int gh = h0 - 1 + lr, gw = w0 - 1 + lc;
        float v = 0.f;
        if ((unsigned)gh < (unsigned)H && (unsigned)gw < (unsigned)W)
            v = depth[((size_t)b * H + gh) * W + gw];
        sD[tid] = v;
    }
    __syncthreads();

    // ---- GEMM1: conv3x3, wave owns px rows 2wv,2wv+1 x 64 oc ----
    frag_cd acc1[2][4];
    #pragma unroll
    for (int mt = 0; mt < 2; ++mt)
        #pragma unroll
        for (int nt = 0; nt < 4; ++nt) acc1[mt][nt] = frag_cd{0.f, 0.f, 0.f, 0.f};

    #pragma unroll
    for (int tap = 0; tap < 9; ++tap) {
        const int ky = tap / 3, kx = tap % 3;
        #pragma unroll
        for (int kh = 0; kh < 2; ++kh) {
            frag_ab a[2];
            #pragma unroll
            for (int mt = 0; mt < 2; ++mt) {
                int r = 2 * wv + mt + ky, col = ln + kx;
                int slot = (r * 18 + col) * 8 + ((kh * 4 + q) ^ (col & 7));
                a[mt] = *(const frag_ab*)&sF[slot * 8];
            }
            frag_ab bf[4];
            #pragma unroll
            for (int nt = 0; nt < 4; ++nt)
                bf[nt] = *(const frag_ab*)&w1bf[(size_t)((tap * 2 + kh) * 4 + q) * 512 + (nt * 16 + ln) * 8];
            #pragma unroll
            for (int mt = 0; mt < 2; ++mt)
                #pragma unroll
                for (int nt = 0; nt < 4; ++nt)
                    acc1[mt][nt] = __builtin_amdgcn_mfma_f32_16x16x32_bf16(a[mt], bf[nt], acc1[mt][nt], 0, 0, 0);
        }
    }

    __syncthreads();   // all waves done reading sF; overlay sH on it

    unsigned short* sH = sF + wv * 2304;   // per-wave [px32][72] bf16 (4608 B slice)
    #pragma unroll
    for (int mt = 0; mt < 2; ++mt)
        #pragma unroll
        for (int nt = 0; nt < 4; ++nt)
            #pragma unroll
            for (int r = 0; r < 4; ++r)
                sH[(mt * 16 + q * 4 + r) * 72 + nt * 16 + ln] = f2bf(fmaxf(acc1[mt][nt][r], 0.f));
    // same-wave LDS RAW: compiler-inserted lgkmcnt, no barrier needed

    // ---- GEMM2: logits, n-tile == tap ----
    frag_cd acc2[2][9];
    #pragma unroll
    for (int mt = 0; mt < 2; ++mt)
        #pragma unroll
        for (int nt = 0; nt < 9; ++nt) acc2[mt][nt] = frag_cd{0.f, 0.f, 0.f, 0.f};

    #pragma unroll
    for (int kh = 0; kh < 2; ++kh) {
        frag_ab a2[2];
        #pragma unroll
        for (int mt = 0; mt < 2; ++mt)
            a2[mt] = *(const frag_ab*)&sH[(mt * 16 + ln) * 72 + kh * 32 + q * 8];
        #pragma unroll
        for (int nt = 0; nt < 9; ++nt) {
            frag_ab b2 = *(const frag_ab*)&w2bf[(size_t)((kh * 4 + q) * 144 + nt * 16 + ln) * 8];
            acc2[0][nt] = __builtin_amdgcn_mfma_f32_16x16x32_bf16(a2[0], b2, acc2[0][nt], 0, 0, 0);
            acc2[1][nt] = __builtin_amdgcn_mfma_f32_16x16x32_bf16(a2[1], b2, acc2[1][nt], 0, 0, 0);
        }
    }

    // ---- softmax over 9 taps + convex combine; stage into own slice ----
    float* sOutw = (float*)sH;   // [px32][17] f32 staging (max idx 542 < 1152 f32 slice)
    #pragma unroll
    for (int mt = 0; mt < 2; ++mt) {
        const int prow = 2 * wv + mt;
        #pragma unroll
        for (int r = 0; r < 4; ++r) {
            const int pcol = q * 4 + r;
            float lg[9];
            #pragma unroll
            for (int t = 0; t < 9; ++t) lg[t] = acc2[mt][t][r];
            float mx = lg[0];
            #pragma unroll
            for (int t = 1; t < 9; ++t) mx = fmaxf(mx, lg[t]);
            float sum = 0.f, up = 0.f;
            #pragma unroll
            for (int t = 0; t < 9; ++t) {
                float e = __expf(lg[t] - mx);
                sum += e;
                up  += e * sD[(prow + t / 3) * 18 + (pcol + t % 3)];
            }
            sOutw[(mt * 16 + pcol) * 17 + ln] = up / sum;
        }
    }
    float* outb = out + (size_t)b * 512 * OW + (size_t)(h0 + 2 * wv) * 4 * OW + w0 * 4;
    const int row_o = lane >> 3;
    const int mt_o  = row_o >> 2, sy_o = row_o & 3;
    #pragma unroll
    for (int v = 0; v < 2; ++v) {
        float4 o;
        #pragma unroll
        for (int e = 0; e < 4; ++e) {
            int j = (lane & 7) * 8 + v * 4 + e;
            o[e] = sOutw[(mt_o * 16 + (j >> 2)) * 17 + sy_o * 4 + (j & 3)];
        }
        *(float4*)&outb[(size_t)row_o * OW + (lane & 7) * 8 + v * 4] = o;
    }
}

// ---------------- fallback (round-2 kernel, self-staged) ----------------
__global__ __launch_bounds__(256, 3) void convex_up_mfma_fb(
    const float* __restrict__ depth, const float* __restrict__ feat,
    const unsigned short* __restrict__ w1bf, const unsigned short* __restrict__ w2bf,
    float* __restrict__ out)
{
    constexpr int H = 128, W = 416, OW = 1664;
    __shared__ unsigned short sF[8 * 10 * 18 * 8];
    __shared__ unsigned short sH[4][32 * 72];
    __shared__ float sD[10 * 18];
    const int tid = threadIdx.x, wv = tid >> 6, lane = tid & 63;
    const int q = lane >> 4, ln = lane & 15;
    const int bw = blockIdx.x, bh = blockIdx.y, b = blockIdx.z;
    const int h0 = bh * 8, w0 = bw * 16;
    if (tid < 180) {
        int lr = tid / 18, lc = tid % 18;
        int gh = h0 - 1 + lr, gw = w0 - 1 + lc;
        float v = 0.f;
        if ((unsigned)gh < (unsigned)H && (unsigned)gw < (unsigned)W)
            v = depth[((size_t)b * H + gh) * W + gw];
        sD[tid] = v;
    }
    for (int idx = tid; idx < 11520; idx += 256) {
        int ic = idx / 180, rem = idx - ic * 180;
        int lr = rem / 18, lc = rem - lr * 18;
        int gh = h0 - 1 + lr, gw = w0 - 1 + lc;
        float v = 0.f;
        if ((unsigned)gh < (unsigned)H && (unsigned)gw < (unsigned)W)
            v = feat[(((size_t)b * 64 + ic) * H + gh) * W + gw];
        sF[(((ic >> 3) * 10 + lr) * 18 + lc) * 8 + (ic & 7)] = f2bf(v);
    }
    __syncthreads();
    frag_cd acc1[2][4];
    for (int mt = 0; mt < 2; ++mt) for (int nt = 0; nt < 4; ++nt) acc1[mt][nt] = frag_cd{0.f,0.f,0.f,0.f};
    #pragma unroll
    for (int tap = 0; tap < 9; ++tap) {
        const int ky = tap / 3, kx = tap % 3;
        #pragma unroll
        for (int kh = 0; kh < 2; ++kh) {
            frag_ab a[2];
            #pragma unroll
            for (int mt = 0; mt < 2; ++mt)
                a[mt] = *(const frag_ab*)&sF[(((kh * 4 + q) * 10 + 2 * wv + mt + ky) * 18 + ln + kx) * 8];
            frag_ab bf[4];
            #pragma unroll
            for (int nt = 0; nt < 4; ++nt)
                bf[nt] = *(const frag_ab*)&w1bf[(size_t)((tap * 2 + kh) * 4 + q) * 512 + (nt * 16 + ln) * 8];
            #pragma unroll
            for (int mt = 0; mt < 2; ++mt)
                #pragma unroll
                for (int nt = 0; nt < 4; ++nt)
                    acc1[mt][nt] = __builtin_amdgcn_mfma_f32_16x16x32_bf16(a[mt], bf[nt], acc1[mt][nt], 0, 0, 0);
        }
    }
    #pragma unroll
    for (int mt = 0; mt < 2; ++mt)
        #pragma unroll
        for (int nt = 0; nt < 4; ++nt)
            #pragma unroll
            for (int r = 0; r < 4; ++r)
                sH[wv][(mt * 16 + q * 4 + r) * 72 + nt * 16 + ln] = f2bf(fmaxf(acc1[mt][nt][r], 0.f));
    frag_cd acc2[2][9];
    for (int mt = 0; mt < 2; ++mt) for (int nt = 0; nt < 9; ++nt) acc2[mt][nt] = frag_cd{0.f,0.f,0.f,0.f};
    #pragma unroll
    for (int kh = 0; kh < 2; ++kh) {
        frag_ab a2[2];
        #pragma unroll
        for (int mt = 0; mt < 2; ++mt)
            a2[mt] = *(const frag_ab*)&sH[wv][(mt * 16 + ln) * 72 + kh * 32 + q * 8];
        #pragma unroll
        for (int nt = 0; nt < 9; ++nt) {
            frag_ab b2 = *(const frag_ab*)&w2bf[(size_t)((kh * 4 + q) * 144 + nt * 16 + ln) * 8];
            acc2[0][nt] = __builtin_amdgcn_mfma_f32_16x16x32_bf16(a2[0], b2, acc2[0][nt], 0, 0, 0);
            acc2[1][nt] = __builtin_amdgcn_mfma_f32_16x16x32_bf16(a2[1], b2, acc2[1][nt], 0, 0, 0);
        }
    }
    float* sOutw = (float*)&sH[wv][0];
    #pragma unroll
    for (int mt = 0; mt < 2; ++mt) {
        const int prow = 2 * wv + mt;
        #pragma unroll
        for (int r = 0; r < 4; ++r) {
            const int pcol = q * 4 + r;
            float lg[9];
            #pragma unroll
            for (int t = 0; t < 9; ++t) lg[t] = acc2[mt][t][r];
            float mx = lg[0];
            #pragma unroll
            for (int t = 1; t < 9; ++t) mx = fmaxf(mx, lg[t]);
            float sum = 0.f, up = 0.f;
            #pragma unroll
            for (int t = 0; t < 9; ++t) {
                float e = __expf(lg[t] - mx);
                sum += e; up += e * sD[(prow + t / 3) * 18 + (pcol + t % 3)];
            }
            sOutw[(mt * 16 + pcol) * 17 + ln] = up / sum;
        }
    }
    float* outb = out + (size_t)b * 512 * OW + (size_t)(h0 + 2 * wv) * 4 * OW + w0 * 4;
    const int row_o = lane >> 3, mt_o = row_o >> 2, sy_o = row_o & 3;
    #pragma unroll
    for (int v = 0; v < 2; ++v) {
        float4 o;
        #pragma unroll
        for (int e = 0; e < 4; ++e) {
            int j = (lane & 7) * 8 + v * 4 + e;
            o[e] = sOutw[(mt_o * 16 + (j >> 2)) * 17 + sy_o * 4 + (j & 3)];
        }
        *(float4*)&outb[(size_t)row_o * OW + (lane & 7) * 8 + v * 4] = o;
    }
}

extern "C" void kernel_launch(void* const* d_in, const int* in_sizes, int n_in,
                              void* d_out, int out_size, void* d_ws, size_t ws_size,
                              hipStream_t stream) {
    const float* depth = (const float*)d_in[0];
    const float* feat  = (const float*)d_in[1];
    const float* w1    = (const float*)d_in[2];
    const float* w2    = (const float*)d_in[3];
    float* out = (float*)d_out;

    const size_t NHWC_USHORTS = (size_t)8 * 130 * 418 * 64;        // 27,827,200
    const size_t NEED = NHWC_USHORTS * 2 + (36864 + 9216) * 2;     // 55,746,560 B

    if (ws_size >= NEED) {
        unsigned short* nhwc = (unsigned short*)d_ws;
        unsigned short* w1bf = nhwc + NHWC_USHORTS;
        unsigned short* w2bf = w1bf + 36864;
        nchw_prep<<<dim3(13, 32, 8), 256, 0, stream>>>(feat, w1, w2, nhwc, w1bf, w2bf);
        convex_up_mfma2<<<dim3(26, 16, 8), dim3(256), 0, stream>>>(depth, nhwc, w1bf, w2bf, out);
    } else {
        unsigned short* w1bf = (unsigned short*)d_ws;
        unsigned short* w2bf = w1bf + 36864;
        prep<<<273, 256, 0, stream>>>(w1, w2, w1bf, w2bf, nullptr, 0);
        convex_up_mfma_fb<<<dim3(26, 16, 8), 256, 0, stream>>>(depth, feat, w1bf, w2bf, out);
    }
}